// Round 11
// baseline (168.141 us; speedup 1.0000x reference)
//
#include <hip/hip_runtime.h>
#include <hip/hip_bf16.h>

#define B_NUM 2
#define T_SEQ 2048
#define C_DIM 1024
#define H_NUM 16
#define HD    64
#define M_TOT 4096
#define BH_N  32

typedef __attribute__((ext_vector_type(8))) short short8;   // 8 bf16
typedef __attribute__((ext_vector_type(4))) float floatx4;  // 4 fp32 acc

__device__ __forceinline__ short f2bf(float f) {
    unsigned u = __float_as_uint(f);
    u += 0x7FFFu + ((u >> 16) & 1u);
    return (short)(u >> 16);
}

__device__ __forceinline__ unsigned pk2bf(float a, float b) {
    float2 f2; f2.x = a; f2.y = b;
    __hip_bfloat162 h = __float22bfloat162_rn(f2);
    unsigned u; __builtin_memcpy(&u, &h, 4); return u;
}

// async global->LDS, 16B per lane; LDS dest = wave-uniform base + lane*16
__device__ __forceinline__ void gld16(const short* g, short* l) {
    __builtin_amdgcn_global_load_lds(
        (const __attribute__((address_space(1))) void*)g,
        (__attribute__((address_space(3))) void*)l, 16, 0, 0);
}

// top-of-iter drain: own prior loads done (full-iter slack) + block barrier.
// raw s_barrier is not an LLVM memory fence -> add compiler fence after so
// the following ds_reads / gld16 issues cannot hoist above it.
__device__ __forceinline__ void drain_barrier() {
    asm volatile("s_waitcnt vmcnt(0)" ::: "memory");
    __builtin_amdgcn_s_barrier();
    asm volatile("" ::: "memory");
}

// ===========================================================================
// prep: x fp32->bf16 (blocks 0..4095, consecutive-lane float4 reads) and
// W/Wp transpose (blocks 4096..5119, f32 LDS staging, col' = c ^ d swizzle).
// ===========================================================================
__global__ __launch_bounds__(256) void prep_k(
    const float* __restrict__ x, const float* __restrict__ Wq,
    const float* __restrict__ Wk, const float* __restrict__ Wv,
    const float* __restrict__ Wp,
    short* __restrict__ xb, short* __restrict__ wt, short* __restrict__ wpt) {
    const int bid = blockIdx.x;
    const int tid = threadIdx.x;
    if (bid < 4096) {
        int idx = (bid * 256 + tid) * 4;
        float4 v = *(const float4*)(x + idx);
        uint2 u; u.x = pk2bf(v.x, v.y); u.y = pk2bf(v.z, v.w);
        *(uint2*)(xb + idx) = u;
        return;
    }
    const int b2 = bid - 4096;
    const int ct = b2 & 15, y = b2 >> 4;
    __shared__ float shf[4096];                 // 64x64 f32, XOR-swizzled cols

    const float* src;
    size_t src_stride;
    int src_col0;
    short* dst;
    int dst_col0;
    if (y < 48) {
        const int which = y >> 4, h = y & 15;
        src = ((which == 0) ? Wq : (which == 1) ? Wk : Wv)
              + (size_t)h * C_DIM * HD + (size_t)(ct * 64) * HD;
        src_stride = HD;  src_col0 = 0;
        dst = wt + (size_t)((which * 16 + h) * 64) * C_DIM;
        dst_col0 = ct * 64;
    } else {
        const int nt = y - 48;
        src = Wp + (size_t)(ct * 64) * C_DIM;
        src_stride = C_DIM;  src_col0 = nt * 64;
        dst = wpt + (size_t)(nt * 64) * C_DIM;
        dst_col0 = ct * 64;
    }
    #pragma unroll
    for (int p = 0; p < 4; ++p) {
        int idx = tid + 256 * p;
        int c = idx >> 4, d4 = idx & 15;
        float4 v = *(const float4*)(src + (size_t)c * src_stride + src_col0 + d4 * 4);
        shf[(d4 * 4 + 0) * 64 + (c ^ (d4 * 4 + 0))] = v.x;
        shf[(d4 * 4 + 1) * 64 + (c ^ (d4 * 4 + 1))] = v.y;
        shf[(d4 * 4 + 2) * 64 + (c ^ (d4 * 4 + 2))] = v.z;
        shf[(d4 * 4 + 3) * 64 + (c ^ (d4 * 4 + 3))] = v.w;
    }
    __syncthreads();
    #pragma unroll
    for (int p = 0; p < 2; ++p) {
        int idx = tid + 256 * p;
        int d = idx >> 3, cc = idx & 7;
        const float* row = shf + d * 64;
        uint4 u;
        u.x = pk2bf(row[(cc * 8 + 0) ^ d], row[(cc * 8 + 1) ^ d]);
        u.y = pk2bf(row[(cc * 8 + 2) ^ d], row[(cc * 8 + 3) ^ d]);
        u.z = pk2bf(row[(cc * 8 + 4) ^ d], row[(cc * 8 + 5) ^ d]);
        u.w = pk2bf(row[(cc * 8 + 6) ^ d], row[(cc * 8 + 7) ^ d]);
        *(uint4*)(dst + (size_t)d * C_DIM + dst_col0 + cc * 8) = u;
    }
}

// ===========================================================================
// qkv: 256x192 tiles, 256 blocks, dbuf. CHANGE vs R10: drain moved from
// end-of-iter (__syncthreads right after issuing next-tile loads -> implicit
// vmcnt(0) stalls on ~300cy-old loads, the documented m97 ~20% stall) to
// TOP-of-iter (vmcnt(0) on full-iter-old loads ~ free + raw s_barrier).
// Still exactly ONE barrier per K-step (R7's 5-barrier split regressed).
// STAGE clumped right after the barrier = maximal in-flight time.
// ===========================================================================
__global__ __launch_bounds__(512, 1) void qkv_k(
    const short* __restrict__ xb, const short* __restrict__ wt,
    short* __restrict__ qb, short* __restrict__ kb, short* __restrict__ vtb) {
    extern __shared__ short smem[];              // 57344 shorts = 112 KiB

    const int swz = (blockIdx.x & 7) * 32 + (blockIdx.x >> 3);  // bijective
    const int mt = swz >> 4, ntg = swz & 15;
    const int m0 = mt * 256, n0 = ntg * 192;

    const int tid = threadIdx.x;
    const int lane = tid & 63, w = tid >> 6;     // 8 waves
    const int wm = w & 1, wn = w >> 1;           // wave tile 128x48
    const int hi = lane >> 4, llo = lane & 15;
    const int lrow = lane >> 3;
    const int lswz = ((lane & 7) ^ (lrow & 7)) * 8;
    const int fc0 = (hi ^ (llo & 7)) * 8;
    const int fc1 = ((hi + 4) ^ (llo & 7)) * 8;

    floatx4 acc[8][3];
    #pragma unroll
    for (int i = 0; i < 8; ++i)
        #pragma unroll
        for (int j = 0; j < 3; ++j)
            #pragma unroll
            for (int r = 0; r < 4; ++r) acc[i][j][r] = 0.0f;

    const size_t a_base = (size_t)(m0 + w * 32 + lrow) * C_DIM + lswz;
    const size_t b_base = (size_t)(n0 + w * 24 + lrow) * C_DIM + lswz;

    auto STAGE = [&](int bsel, int kt) {
        const int c0 = kt * 64;
        short* Ad = smem + bsel * 16384;
        short* Bd = smem + 32768 + bsel * 12288;
        #pragma unroll
        for (int p = 0; p < 4; ++p)
            gld16(xb + a_base + (size_t)p * 8 * C_DIM + c0, &Ad[(w * 32 + p * 8) * 64]);
        #pragma unroll
        for (int p = 0; p < 3; ++p)
            gld16(wt + b_base + (size_t)p * 8 * C_DIM + c0, &Bd[(w * 24 + p * 8) * 64]);
    };

    STAGE(0, 0);

    for (int kt = 0; kt < 16; ++kt) {
        const int cur = kt & 1;
        drain_barrier();                         // buf[cur] ready; buf[cur^1] free
        if (kt < 15) STAGE(cur ^ 1, kt + 1);     // full compute phase in flight

        const short* As = smem + cur * 16384;
        const short* Bs = smem + 32768 + cur * 12288;

        short8 bf[3][2];
        #pragma unroll
        for (int ni = 0; ni < 3; ++ni) {
            const int row = wn * 48 + ni * 16 + llo;
            bf[ni][0] = *(const short8*)(&Bs[row * 64 + fc0]);
            bf[ni][1] = *(const short8*)(&Bs[row * 64 + fc1]);
        }
        #pragma unroll
        for (int mi = 0; mi < 8; ++mi) {
            const int row = wm * 128 + mi * 16 + llo;
            short8 a0 = *(const short8*)(&As[row * 64 + fc0]);
            short8 a1 = *(const short8*)(&As[row * 64 + fc1]);
            #pragma unroll
            for (int ni = 0; ni < 3; ++ni) {
                acc[mi][ni] = __builtin_amdgcn_mfma_f32_16x16x32_bf16(a0, bf[ni][0], acc[mi][ni], 0, 0, 0);
                acc[mi][ni] = __builtin_amdgcn_mfma_f32_16x16x32_bf16(a1, bf[ni][1], acc[mi][ni], 0, 0, 0);
            }
        }
    }
    __syncthreads();                             // before smem reuse (epilogue)

    const int bb = m0 >> 11;
    #pragma unroll
    for (int c = 0; c < 3; ++c) {
        const int nch = n0 + c * 64;
        const int which = nch >> 10;
        const int h = (nch >> 6) & 15;
        __syncthreads();
        if (which == 2) {
            short (*R2)[268] = (short(*)[268])smem;
            #pragma unroll
            for (int ni = 0; ni < 3; ++ni) {
                const int gcol = wn * 48 + ni * 16;
                if ((gcol >> 6) == c) {
                    #pragma unroll
                    for (int mi = 0; mi < 8; ++mi)
                        #pragma unroll
                        for (int r = 0; r < 4; ++r)
                            R2[(gcol & 63) + llo][wm * 128 + mi * 16 + hi * 4 + r] =
                                f2bf(acc[mi][ni][r]);
                }
            }
            __syncthreads();
            #pragma unroll
            for (int p = 0; p < 4; ++p) {
                int idx = tid + 512 * p;
                int d = idx >> 5, cc = idx & 31;
                short8 vv = *(const short8*)(&R2[d][cc * 8]);
                *(short8*)(vtb + ((size_t)((bb * H_NUM + h) * HD + d)) * T_SEQ
                           + (m0 & 2047) + cc * 8) = vv;
            }
        } else {
            short (*R)[76] = (short(*)[76])smem;
            const float scl = (which == 0) ? 0.125f * 1.4426950408889634f : 1.0f;
            short* outp = (which == 0) ? qb : kb;
            #pragma unroll
            for (int ni = 0; ni < 3; ++ni) {
                const int gcol = wn * 48 + ni * 16;
                if ((gcol >> 6) == c) {
                    #pragma unroll
                    for (int mi = 0; mi < 8; ++mi)
                        #pragma unroll
                        for (int r = 0; r < 4; ++r)
                            R[wm * 128 + mi * 16 + hi * 4 + r][(gcol & 63) + llo] =
                                f2bf(acc[mi][ni][r] * scl);
                }
            }
            __syncthreads();
            #pragma unroll
            for (int p = 0; p < 4; ++p) {
                int idx = tid + 512 * p;
                int rr = idx >> 3, cc = idx & 7;
                short8 vv = *(const short8*)(&R[rr][cc * 8]);
                int t = (m0 + rr) & 2047;
                *(short8*)(outp + ((size_t)(bb * H_NUM + h) * T_SEQ + t) * HD + cc * 8) = vv;
            }
        }
    }
}

// ===========================================================================
// attn: EXACT R4 version (proven best). Its __syncthreads is already at
// top-of-iter = drain-at-top with full-iter slack; left untouched.
// ===========================================================================
__global__ __launch_bounds__(512) void attn_k(
    const short* __restrict__ qb, const short* __restrict__ kb,
    const short* __restrict__ vtb, short* __restrict__ attb) {
    const int bh = blockIdx.x;
    const int y = blockIdx.y;
    const int qt = (y < 8) ? (15 - y) : (y - 8);
    const int b = bh >> 4, h = bh & 15;
    const short* K  = kb  + (size_t)bh * T_SEQ * HD;
    const short* Vt = vtb + (size_t)bh * HD * T_SEQ;

    __shared__ short Ks[2][4096];
    __shared__ short Vs[2][4096];
    __shared__ short Ps[128][76];

    const int tid = threadIdx.x;
    const int lane = tid & 63, w = tid >> 6;
    const int hi = lane >> 4, llo = lane & 15;
    const int lrow = lane >> 3;
    const int lswz = ((lane & 7) ^ (lrow & 7)) * 8;
    const int fc0 = (hi ^ (llo & 7)) * 8;
    const int fc1 = ((hi + 4) ^ (llo & 7)) * 8;
    const int kmax = 2 * qt + 1;

    short8 qf[2];
    const int qcol0 = qt * 128 + w * 16;
    #pragma unroll
    for (int kh = 0; kh < 2; ++kh)
        qf[kh] = *(const short8*)(qb +
            ((size_t)bh * T_SEQ + qcol0 + llo) * HD + kh * 32 + hi * 8);

    short8 av4;
    #pragma unroll
    for (int j = 0; j < 8; ++j) av4[j] = (llo == 0) ? (short)0x3F80 : (short)0;

    gld16(K + (size_t)(w * 8 + lrow) * HD + lswz, &Ks[0][(w * 8) * 64]);
    gld16(Vt + (size_t)(w * 8 + lrow) * T_SEQ + lswz, &Vs[0][(w * 8) * 64]);

    floatx4 Oa[5];
    #pragma unroll
    for (int n = 0; n < 5; ++n)
        #pragma unroll
        for (int r = 0; r < 4; ++r) Oa[n][r] = 0.0f;

    for (int kt = 0; kt <= kmax; ++kt) {
        __syncthreads();
        const int buf = kt & 1;

        if (kt + 1 <= kmax) {
            const int s0 = (kt + 1) * 64;
            const int nb = buf ^ 1;
            gld16(K + ((size_t)s0 + w * 8 + lrow) * HD + lswz, &Ks[nb][(w * 8) * 64]);
            gld16(Vt + (size_t)(w * 8 + lrow) * T_SEQ + s0 + lswz, &Vs[nb][(w * 8) * 64]);
        }

        short8 ak[4][2];
        #pragma unroll
        for (int nt = 0; nt < 4; ++nt) {
            const int row = nt * 16 + llo;
            ak[nt][0] = *(const short8*)(&Ks[buf][row * 64 + fc0]);
            ak[nt][1] = *(const short8*)(&Ks[buf][row * 64 + fc1]);
        }
        floatx4 sf[4];
        #pragma unroll
        for (int nt = 0; nt < 4; ++nt)
            #pragma unroll
            for (int r = 0; r < 4; ++r) sf[nt][r] = 0.0f;
        __builtin_amdgcn_s_setprio(1);
        #pragma unroll
        for (int nt = 0; nt < 4; ++nt)
            #pragma unroll
            for (int kh = 0; kh < 2; ++kh)
                sf[nt] = __builtin_amdgcn_mfma_f32_16x16x32_bf16(
                    ak[nt][kh], qf[kh], sf[nt], 0, 0, 0);
        __builtin_amdgcn_s_setprio(0);

        const int sbase = kt * 64;
        if (sbase + 63 > qcol0) {
            const int qlane = qcol0 + llo;
            #pragma unroll
            for (int nt = 0; nt < 4; ++nt)
                #pragma unroll
                for (int r = 0; r < 4; ++r)
                    if (sbase + nt * 16 + hi * 4 + r > qlane) sf[nt][r] = -3.0e38f;
        }

        #pragma unroll
        for (int nt = 0; nt < 4; ++nt) {
            float p0 = __builtin_amdgcn_exp2f(sf[nt][0]);
            float p1 = __builtin_amdgcn_exp2f(sf[nt][1]);
            float p2 = __builtin_amdgcn_exp2f(sf[nt][2]);
            float p3 = __builtin_amdgcn_exp2f(sf[nt][3]);
            uint2 u; u.x = pk2bf(p0, p1); u.y = pk2bf(p2, p3);
            *(uint2*)(&Ps[w * 16 + llo][nt * 16 + hi * 4]) = u;
        }

        short8 av[5][2];
        #pragma unroll
        for (int nt2 = 0; nt2 < 4; ++nt2) {
            const int row = nt2 * 16 + llo;
            av[nt2][0] = *(const short8*)(&Vs[buf][row * 64 + fc0]);
            av[nt2][1] = *(const short8*)(&Vs[buf][row * 64 + fc1]);
        }
        av[4][0] = av4;
        av[4][1] = av4;
        short8 bpf[2];
        #pragma unroll
        for (int kh = 0; kh < 2; ++kh)
            bpf[kh] = *(const short8*)(&Ps[w * 16 + llo][kh * 32 + hi * 8]);
        __builtin_amdgcn_s_setprio(1);
        #pragma unroll
        for (int nt2 = 0; nt2 < 5; ++nt2)
            #pragma unroll
            for (int kh = 0; kh < 2; ++kh)
                Oa[nt2] = __builtin_amdgcn_mfma_f32_16x16x32_bf16(
                    av[nt2][kh], bpf[kh], Oa[nt2], 0, 0, 0);
        __builtin_amdgcn_s_setprio(0);
    }

    {
        float lb = __shfl(Oa[4][0], llo);
        float inv = 1.0f / lb;
        #pragma unroll
        for (int nt2 = 0; nt2 < 4; ++nt2) {
            uint2 u;
            u.x = pk2bf(Oa[nt2][0] * inv, Oa[nt2][1] * inv);
            u.y = pk2bf(Oa[nt2][2] * inv, Oa[nt2][3] * inv);
            *(uint2*)(&Ps[w * 16 + llo][nt2 * 16 + hi * 4]) = u;
        }
    }
    __syncthreads();
    #pragma unroll
    for (int p = 0; p < 2; ++p) {
        int idx = tid + 512 * p;
        int r = idx >> 3, cc = idx & 7;
        short8 vv = *(const short8*)(&Ps[r][cc * 8]);
        *(short8*)(attb + ((size_t)(b * T_SEQ + qt * 128 + r)) * C_DIM + h * HD + cc * 8) = vv;
    }
}

// ===========================================================================
// proj: 128x128 tiles, 512 threads / 8 waves (R10), dbuf with the same
// drain-at-top single-barrier loop as qkv. Epilogue writes regs->global
// only, so no trailing barrier needed.
// ===========================================================================
__global__ __launch_bounds__(512, 2) void proj_k(
    const short* __restrict__ attb, const short* __restrict__ wpt,
    const float* __restrict__ bp, float* __restrict__ out) {
    const int mt = blockIdx.x, ntg = blockIdx.y;
    const int m0 = mt * 128, n0 = ntg * 128;

    __shared__ short smem[32768];                // A0 A1 B0 B1, 8192 shorts each

    const int tid = threadIdx.x;
    const int lane = tid & 63, w = tid >> 6;     // 8 waves
    const int wm = w & 3, wn = w >> 2;           // 4M x 2N, wave tile 32x64
    const int hi = lane >> 4, llo = lane & 15;
    const int lrow = lane >> 3;
    const int lswz = ((lane & 7) ^ (lrow & 7)) * 8;
    const int fc0 = (hi ^ (llo & 7)) * 8;
    const int fc1 = ((hi + 4) ^ (llo & 7)) * 8;

    floatx4 acc[2][4];
    #pragma unroll
    for (int i = 0; i < 2; ++i)
        #pragma unroll
        for (int j = 0; j < 4; ++j)
            #pragma unroll
            for (int r = 0; r < 4; ++r) acc[i][j][r] = 0.0f;

    const size_t a_base = (size_t)(m0 + w * 16 + lrow) * C_DIM + lswz;
    const size_t b_base = (size_t)(n0 + w * 16 + lrow) * C_DIM + lswz;

    auto STAGE = [&](int bsel, int kt) {
        const int c0 = kt * 64;
        short* Ad = smem + bsel * 8192;
        short* Bd = smem + 16384 + bsel * 8192;
        #pragma unroll
        for (int p = 0; p < 2; ++p) {
            gld16(attb + a_base + (size_t)p * 8 * C_DIM + c0, &Ad[(w * 16 + p * 8) * 64]);
            gld16(wpt  + b_base + (size_t)p * 8 * C_DIM + c0, &Bd[(w * 16 + p * 8) * 64]);
        }
    };

    STAGE(0, 0);

    for (int kt = 0; kt < 16; ++kt) {
        const int cur = kt & 1;
        drain_barrier();                         // buf[cur] ready; buf[cur^1] free
        if (kt < 15) STAGE(cur ^ 1, kt + 1);

        const short* As = smem + cur * 8192;
        const short* Bs = smem + 16384 + cur * 8192;

        short8 af[2][2];
        #pragma unroll
        for (int mi = 0; mi < 2; ++mi) {
            const int row = wm * 32 + mi * 16 + llo;
            af[mi][0] = *(const short8*)(&As[row * 64 + fc0]);
            af[mi][1] = *(const short8*)(&As[row * 64 + fc1]);
        }
        #pragma unroll
        for (int ni = 0; ni < 4; ++ni) {
            const int row = wn * 64 + ni * 16 + llo;
            short8 b0 = *(const short8*)(&Bs[row * 64 + fc0]);
            short8 b1 = *(const short8*)(&Bs[row * 64 + fc1]);
            #pragma unroll
            for (int mi = 0; mi < 2; ++mi) {
                acc[mi][ni] = __builtin_amdgcn_mfma_f32_16x16x32_bf16(af[mi][0], b0, acc[mi][ni], 0, 0, 0);
                acc[mi][ni] = __builtin_amdgcn_mfma_f32_16x16x32_bf16(af[mi][1], b1, acc[mi][ni], 0, 0, 0);
            }
        }
    }

    #pragma unroll
    for (int ni = 0; ni < 4; ++ni) {
        const int n = n0 + wn * 64 + ni * 16 + llo;
        const float bias = bp[n];
        #pragma unroll
        for (int mi = 0; mi < 2; ++mi)
            #pragma unroll
            for (int r = 0; r < 4; ++r) {
                int m = m0 + wm * 32 + mi * 16 + hi * 4 + r;
                out[(size_t)m * C_DIM + n] = acc[mi][ni][r] + bias;
            }
    }
}

// ---------------------------------------------------------------------------
extern "C" void kernel_launch(void* const* d_in, const int* in_sizes, int n_in,
                              void* d_out, int out_size, void* d_ws, size_t ws_size,
                              hipStream_t stream) {
    const float* x  = (const float*)d_in[0];
    const float* Wq = (const float*)d_in[1];
    const float* Wk = (const float*)d_in[2];
    const float* Wv = (const float*)d_in[3];
    const float* Wp = (const float*)d_in[4];
    const float* bp = (const float*)d_in[5];
    float* out = (float*)d_out;

    short* xb   = (short*)d_ws;
    short* wt   = xb  + (size_t)M_TOT * C_DIM;
    short* wpt  = wt  + (size_t)3 * H_NUM * HD * C_DIM;
    short* qb   = wpt + (size_t)C_DIM * C_DIM;
    short* kb   = qb  + (size_t)M_TOT * C_DIM;
    short* vtb  = kb  + (size_t)M_TOT * C_DIM;
    short* attb = vtb + (size_t)M_TOT * C_DIM;

    static bool attr_done = false;
    if (!attr_done) {
        (void)hipFuncSetAttribute((const void*)qkv_k,
                                  hipFuncAttributeMaxDynamicSharedMemorySize,
                                  114688);
        attr_done = true;
    }

    prep_k<<<dim3(5120), 256, 0, stream>>>(x, Wq, Wk, Wv, Wp, xb, wt, wpt);
    qkv_k <<<dim3(256), 512, 114688, stream>>>(xb, wt, qb, kb, vtb);
    attn_k<<<dim3(BH_N, 16), 512, 0, stream>>>(qb, kb, vtb, attb);
    proj_k<<<dim3(M_TOT / 128, C_DIM / 128), 512, 0, stream>>>(attb, wpt, bp, out);
}

// Round 12
// 165.129 us; speedup vs baseline: 1.0182x; 1.0182x over previous
//
#include <hip/hip_runtime.h>
#include <hip/hip_bf16.h>

#define B_NUM 2
#define T_SEQ 2048
#define C_DIM 1024
#define H_NUM 16
#define HD    64
#define M_TOT 4096
#define BH_N  32

typedef __attribute__((ext_vector_type(8))) short short8;   // 8 bf16
typedef __attribute__((ext_vector_type(4))) float floatx4;  // 4 fp32 acc

__device__ __forceinline__ short f2bf(float f) {
    unsigned u = __float_as_uint(f);
    u += 0x7FFFu + ((u >> 16) & 1u);
    return (short)(u >> 16);
}

__device__ __forceinline__ unsigned pk2bf(float a, float b) {
    float2 f2; f2.x = a; f2.y = b;
    __hip_bfloat162 h = __float22bfloat162_rn(f2);
    unsigned u; __builtin_memcpy(&u, &h, 4); return u;
}

// async global->LDS, 16B per lane; LDS dest = wave-uniform base + lane*16
__device__ __forceinline__ void gld16(const short* g, short* l) {
    __builtin_amdgcn_global_load_lds(
        (const __attribute__((address_space(1))) void*)g,
        (__attribute__((address_space(3))) void*)l, 16, 0, 0);
}

// ===========================================================================
// MEASURED-BEST CONFIGURATION (R10, 165.5 us). Session findings baked in:
//  - dbuf with STAGE-before-compute + ONE end-of-iter __syncthreads is the
//    sweet spot (R4/R9); phase-splits, drain-moves, raw-barrier schedules
//    all regressed (R7 -20%, R11 -2%).
//  - occupancy >= 2 waves/SIMD is the binding TLP floor for every kernel
//    (R5/R6 attn restructures and R2 proj lost by cutting it).
//  - attn: Ps-LDS roundtrip beats in-lane K=16 PV (R8: +4.45M bank
//    conflicts, 2x MFMA issues).
// ===========================================================================

// prep: x fp32->bf16 (blocks 0..4095, consecutive-lane float4 reads) and
// W/Wp transpose (blocks 4096..5119, f32 LDS staging, col' = c ^ d swizzle).
__global__ __launch_bounds__(256) void prep_k(
    const float* __restrict__ x, const float* __restrict__ Wq,
    const float* __restrict__ Wk, const float* __restrict__ Wv,
    const float* __restrict__ Wp,
    short* __restrict__ xb, short* __restrict__ wt, short* __restrict__ wpt) {
    const int bid = blockIdx.x;
    const int tid = threadIdx.x;
    if (bid < 4096) {
        int idx = (bid * 256 + tid) * 4;
        float4 v = *(const float4*)(x + idx);
        uint2 u; u.x = pk2bf(v.x, v.y); u.y = pk2bf(v.z, v.w);
        *(uint2*)(xb + idx) = u;
        return;
    }
    const int b2 = bid - 4096;
    const int ct = b2 & 15, y = b2 >> 4;
    __shared__ float shf[4096];                 // 64x64 f32, XOR-swizzled cols

    const float* src;
    size_t src_stride;
    int src_col0;
    short* dst;
    int dst_col0;
    if (y < 48) {
        const int which = y >> 4, h = y & 15;
        src = ((which == 0) ? Wq : (which == 1) ? Wk : Wv)
              + (size_t)h * C_DIM * HD + (size_t)(ct * 64) * HD;
        src_stride = HD;  src_col0 = 0;
        dst = wt + (size_t)((which * 16 + h) * 64) * C_DIM;
        dst_col0 = ct * 64;
    } else {
        const int nt = y - 48;
        src = Wp + (size_t)(ct * 64) * C_DIM;
        src_stride = C_DIM;  src_col0 = nt * 64;
        dst = wpt + (size_t)(nt * 64) * C_DIM;
        dst_col0 = ct * 64;
    }
    #pragma unroll
    for (int p = 0; p < 4; ++p) {
        int idx = tid + 256 * p;
        int c = idx >> 4, d4 = idx & 15;
        float4 v = *(const float4*)(src + (size_t)c * src_stride + src_col0 + d4 * 4);
        shf[(d4 * 4 + 0) * 64 + (c ^ (d4 * 4 + 0))] = v.x;
        shf[(d4 * 4 + 1) * 64 + (c ^ (d4 * 4 + 1))] = v.y;
        shf[(d4 * 4 + 2) * 64 + (c ^ (d4 * 4 + 2))] = v.z;
        shf[(d4 * 4 + 3) * 64 + (c ^ (d4 * 4 + 3))] = v.w;
    }
    __syncthreads();
    #pragma unroll
    for (int p = 0; p < 2; ++p) {
        int idx = tid + 256 * p;
        int d = idx >> 3, cc = idx & 7;
        const float* row = shf + d * 64;
        uint4 u;
        u.x = pk2bf(row[(cc * 8 + 0) ^ d], row[(cc * 8 + 1) ^ d]);
        u.y = pk2bf(row[(cc * 8 + 2) ^ d], row[(cc * 8 + 3) ^ d]);
        u.z = pk2bf(row[(cc * 8 + 4) ^ d], row[(cc * 8 + 5) ^ d]);
        u.w = pk2bf(row[(cc * 8 + 6) ^ d], row[(cc * 8 + 7) ^ d]);
        *(uint4*)(dst + (size_t)d * C_DIM + dst_col0 + cc * 8) = u;
    }
}

// qkv: 256x192 tiles, 256 blocks, dbuf with spread staging (R9/R10 best).
__global__ __launch_bounds__(512, 1) void qkv_k(
    const short* __restrict__ xb, const short* __restrict__ wt,
    short* __restrict__ qb, short* __restrict__ kb, short* __restrict__ vtb) {
    extern __shared__ short smem[];              // 57344 shorts = 112 KiB

    const int swz = (blockIdx.x & 7) * 32 + (blockIdx.x >> 3);  // bijective
    const int mt = swz >> 4, ntg = swz & 15;
    const int m0 = mt * 256, n0 = ntg * 192;

    const int tid = threadIdx.x;
    const int lane = tid & 63, w = tid >> 6;     // 8 waves
    const int wm = w & 1, wn = w >> 1;           // wave tile 128x48
    const int hi = lane >> 4, llo = lane & 15;
    const int lrow = lane >> 3;
    const int lswz = ((lane & 7) ^ (lrow & 7)) * 8;
    const int fc0 = (hi ^ (llo & 7)) * 8;
    const int fc1 = ((hi + 4) ^ (llo & 7)) * 8;

    floatx4 acc[8][3];
    #pragma unroll
    for (int i = 0; i < 8; ++i)
        #pragma unroll
        for (int j = 0; j < 3; ++j)
            #pragma unroll
            for (int r = 0; r < 4; ++r) acc[i][j][r] = 0.0f;

    const size_t a_base = (size_t)(m0 + w * 32 + lrow) * C_DIM + lswz;
    const size_t b_base = (size_t)(n0 + w * 24 + lrow) * C_DIM + lswz;

    auto STAGE_PART = [&](int bsel, int kt, int part) {
        const int c0 = kt * 64;
        short* Ad = smem + bsel * 16384;
        short* Bd = smem + 32768 + bsel * 12288;
        if (part == 0) {
            gld16(xb + a_base + (size_t)0 * 8 * C_DIM + c0, &Ad[(w * 32 + 0) * 64]);
            gld16(xb + a_base + (size_t)1 * 8 * C_DIM + c0, &Ad[(w * 32 + 8) * 64]);
        } else if (part == 1) {
            gld16(xb + a_base + (size_t)2 * 8 * C_DIM + c0, &Ad[(w * 32 + 16) * 64]);
            gld16(xb + a_base + (size_t)3 * 8 * C_DIM + c0, &Ad[(w * 32 + 24) * 64]);
        } else if (part == 2) {
            gld16(wt + b_base + (size_t)0 * 8 * C_DIM + c0, &Bd[(w * 24 + 0) * 64]);
            gld16(wt + b_base + (size_t)1 * 8 * C_DIM + c0, &Bd[(w * 24 + 8) * 64]);
        } else {
            gld16(wt + b_base + (size_t)2 * 8 * C_DIM + c0, &Bd[(w * 24 + 16) * 64]);
        }
    };

    #pragma unroll
    for (int p = 0; p < 4; ++p) STAGE_PART(0, 0, p);
    __syncthreads();

    for (int kt = 0; kt < 16; ++kt) {
        const int cur = kt & 1;
        const int nxt = cur ^ 1;
        const bool more = (kt < 15);

        const short* As = smem + cur * 16384;
        const short* Bs = smem + 32768 + cur * 12288;

        if (more) STAGE_PART(nxt, kt + 1, 0);

        short8 bf[3][2];
        #pragma unroll
        for (int ni = 0; ni < 3; ++ni) {
            const int row = wn * 48 + ni * 16 + llo;
            bf[ni][0] = *(const short8*)(&Bs[row * 64 + fc0]);
            bf[ni][1] = *(const short8*)(&Bs[row * 64 + fc1]);
        }

        #pragma unroll
        for (int mc = 0; mc < 4; ++mc) {
            #pragma unroll
            for (int m2 = 0; m2 < 2; ++m2) {
                const int mi = mc * 2 + m2;
                const int row = wm * 128 + mi * 16 + llo;
                short8 a0 = *(const short8*)(&As[row * 64 + fc0]);
                short8 a1 = *(const short8*)(&As[row * 64 + fc1]);
                #pragma unroll
                for (int ni = 0; ni < 3; ++ni) {
                    acc[mi][ni] = __builtin_amdgcn_mfma_f32_16x16x32_bf16(a0, bf[ni][0], acc[mi][ni], 0, 0, 0);
                    acc[mi][ni] = __builtin_amdgcn_mfma_f32_16x16x32_bf16(a1, bf[ni][1], acc[mi][ni], 0, 0, 0);
                }
            }
            if (more && mc < 3) STAGE_PART(nxt, kt + 1, mc + 1);
        }
        __syncthreads();
    }

    const int bb = m0 >> 11;
    #pragma unroll
    for (int c = 0; c < 3; ++c) {
        const int nch = n0 + c * 64;
        const int which = nch >> 10;
        const int h = (nch >> 6) & 15;
        __syncthreads();
        if (which == 2) {
            short (*R2)[268] = (short(*)[268])smem;
            #pragma unroll
            for (int ni = 0; ni < 3; ++ni) {
                const int gcol = wn * 48 + ni * 16;
                if ((gcol >> 6) == c) {
                    #pragma unroll
                    for (int mi = 0; mi < 8; ++mi)
                        #pragma unroll
                        for (int r = 0; r < 4; ++r)
                            R2[(gcol & 63) + llo][wm * 128 + mi * 16 + hi * 4 + r] =
                                f2bf(acc[mi][ni][r]);
                }
            }
            __syncthreads();
            #pragma unroll
            for (int p = 0; p < 4; ++p) {
                int idx = tid + 512 * p;
                int d = idx >> 5, cc = idx & 31;
                short8 vv = *(const short8*)(&R2[d][cc * 8]);
                *(short8*)(vtb + ((size_t)((bb * H_NUM + h) * HD + d)) * T_SEQ
                           + (m0 & 2047) + cc * 8) = vv;
            }
        } else {
            short (*R)[76] = (short(*)[76])smem;
            const float scl = (which == 0) ? 0.125f * 1.4426950408889634f : 1.0f;
            short* outp = (which == 0) ? qb : kb;
            #pragma unroll
            for (int ni = 0; ni < 3; ++ni) {
                const int gcol = wn * 48 + ni * 16;
                if ((gcol >> 6) == c) {
                    #pragma unroll
                    for (int mi = 0; mi < 8; ++mi)
                        #pragma unroll
                        for (int r = 0; r < 4; ++r)
                            R[wm * 128 + mi * 16 + hi * 4 + r][(gcol & 63) + llo] =
                                f2bf(acc[mi][ni][r] * scl);
                }
            }
            __syncthreads();
            #pragma unroll
            for (int p = 0; p < 4; ++p) {
                int idx = tid + 512 * p;
                int rr = idx >> 3, cc = idx & 7;
                short8 vv = *(const short8*)(&R[rr][cc * 8]);
                int t = (m0 + rr) & 2047;
                *(short8*)(outp + ((size_t)(bb * H_NUM + h) * T_SEQ + t) * HD + cc * 8) = vv;
            }
        }
    }
}

// attn: EXACT R4 version (proven best). 8 waves, 128-q tile, (32,16) grid.
__global__ __launch_bounds__(512) void attn_k(
    const short* __restrict__ qb, const short* __restrict__ kb,
    const short* __restrict__ vtb, short* __restrict__ attb) {
    const int bh = blockIdx.x;
    const int y = blockIdx.y;
    const int qt = (y < 8) ? (15 - y) : (y - 8);
    const int b = bh >> 4, h = bh & 15;
    const short* K  = kb  + (size_t)bh * T_SEQ * HD;
    const short* Vt = vtb + (size_t)bh * HD * T_SEQ;

    __shared__ short Ks[2][4096];
    __shared__ short Vs[2][4096];
    __shared__ short Ps[128][76];

    const int tid = threadIdx.x;
    const int lane = tid & 63, w = tid >> 6;
    const int hi = lane >> 4, llo = lane & 15;
    const int lrow = lane >> 3;
    const int lswz = ((lane & 7) ^ (lrow & 7)) * 8;
    const int fc0 = (hi ^ (llo & 7)) * 8;
    const int fc1 = ((hi + 4) ^ (llo & 7)) * 8;
    const int kmax = 2 * qt + 1;

    short8 qf[2];
    const int qcol0 = qt * 128 + w * 16;
    #pragma unroll
    for (int kh = 0; kh < 2; ++kh)
        qf[kh] = *(const short8*)(qb +
            ((size_t)bh * T_SEQ + qcol0 + llo) * HD + kh * 32 + hi * 8);

    short8 av4;
    #pragma unroll
    for (int j = 0; j < 8; ++j) av4[j] = (llo == 0) ? (short)0x3F80 : (short)0;

    gld16(K + (size_t)(w * 8 + lrow) * HD + lswz, &Ks[0][(w * 8) * 64]);
    gld16(Vt + (size_t)(w * 8 + lrow) * T_SEQ + lswz, &Vs[0][(w * 8) * 64]);

    floatx4 Oa[5];
    #pragma unroll
    for (int n = 0; n < 5; ++n)
        #pragma unroll
        for (int r = 0; r < 4; ++r) Oa[n][r] = 0.0f;

    for (int kt = 0; kt <= kmax; ++kt) {
        __syncthreads();
        const int buf = kt & 1;

        if (kt + 1 <= kmax) {
            const int s0 = (kt + 1) * 64;
            const int nb = buf ^ 1;
            gld16(K + ((size_t)s0 + w * 8 + lrow) * HD + lswz, &Ks[nb][(w * 8) * 64]);
            gld16(Vt + (size_t)(w * 8 + lrow) * T_SEQ + s0 + lswz, &Vs[nb][(w * 8) * 64]);
        }

        short8 ak[4][2];
        #pragma unroll
        for (int nt = 0; nt < 4; ++nt) {
            const int row = nt * 16 + llo;
            ak[nt][0] = *(const short8*)(&Ks[buf][row * 64 + fc0]);
            ak[nt][1] = *(const short8*)(&Ks[buf][row * 64 + fc1]);
        }
        floatx4 sf[4];
        #pragma unroll
        for (int nt = 0; nt < 4; ++nt)
            #pragma unroll
            for (int r = 0; r < 4; ++r) sf[nt][r] = 0.0f;
        __builtin_amdgcn_s_setprio(1);
        #pragma unroll
        for (int nt = 0; nt < 4; ++nt)
            #pragma unroll
            for (int kh = 0; kh < 2; ++kh)
                sf[nt] = __builtin_amdgcn_mfma_f32_16x16x32_bf16(
                    ak[nt][kh], qf[kh], sf[nt], 0, 0, 0);
        __builtin_amdgcn_s_setprio(0);

        const int sbase = kt * 64;
        if (sbase + 63 > qcol0) {
            const int qlane = qcol0 + llo;
            #pragma unroll
            for (int nt = 0; nt < 4; ++nt)
                #pragma unroll
                for (int r = 0; r < 4; ++r)
                    if (sbase + nt * 16 + hi * 4 + r > qlane) sf[nt][r] = -3.0e38f;
        }

        #pragma unroll
        for (int nt = 0; nt < 4; ++nt) {
            float p0 = __builtin_amdgcn_exp2f(sf[nt][0]);
            float p1 = __builtin_amdgcn_exp2f(sf[nt][1]);
            float p2 = __builtin_amdgcn_exp2f(sf[nt][2]);
            float p3 = __builtin_amdgcn_exp2f(sf[nt][3]);
            uint2 u; u.x = pk2bf(p0, p1); u.y = pk2bf(p2, p3);
            *(uint2*)(&Ps[w * 16 + llo][nt * 16 + hi * 4]) = u;
        }

        short8 av[5][2];
        #pragma unroll
        for (int nt2 = 0; nt2 < 4; ++nt2) {
            const int row = nt2 * 16 + llo;
            av[nt2][0] = *(const short8*)(&Vs[buf][row * 64 + fc0]);
            av[nt2][1] = *(const short8*)(&Vs[buf][row * 64 + fc1]);
        }
        av[4][0] = av4;
        av[4][1] = av4;
        short8 bpf[2];
        #pragma unroll
        for (int kh = 0; kh < 2; ++kh)
            bpf[kh] = *(const short8*)(&Ps[w * 16 + llo][kh * 32 + hi * 8]);
        __builtin_amdgcn_s_setprio(1);
        #pragma unroll
        for (int nt2 = 0; nt2 < 5; ++nt2)
            #pragma unroll
            for (int kh = 0; kh < 2; ++kh)
                Oa[nt2] = __builtin_amdgcn_mfma_f32_16x16x32_bf16(
                    av[nt2][kh], bpf[kh], Oa[nt2], 0, 0, 0);
        __builtin_amdgcn_s_setprio(0);
    }

    {
        float lb = __shfl(Oa[4][0], llo);
        float inv = 1.0f / lb;
        #pragma unroll
        for (int nt2 = 0; nt2 < 4; ++nt2) {
            uint2 u;
            u.x = pk2bf(Oa[nt2][0] * inv, Oa[nt2][1] * inv);
            u.y = pk2bf(Oa[nt2][2] * inv, Oa[nt2][3] * inv);
            *(uint2*)(&Ps[w * 16 + llo][nt2 * 16 + hi * 4]) = u;
        }
    }
    __syncthreads();
    #pragma unroll
    for (int p = 0; p < 2; ++p) {
        int idx = tid + 512 * p;
        int r = idx >> 3, cc = idx & 7;
        short8 vv = *(const short8*)(&Ps[r][cc * 8]);
        *(short8*)(attb + ((size_t)(b * T_SEQ + qt * 128 + r)) * C_DIM + h * HD + cc * 8) = vv;
    }
}

// proj: 128x128 tiles, 512 threads / 8 waves, dbuf (R10 best).
__global__ __launch_bounds__(512, 2) void proj_k(
    const short* __restrict__ attb, const short* __restrict__ wpt,
    const float* __restrict__ bp, float* __restrict__ out) {
    const int mt = blockIdx.x, ntg = blockIdx.y;
    const int m0 = mt * 128, n0 = ntg * 128;

    __shared__ short smem[32768];                // A0 A1 B0 B1, 8192 shorts each

    const int tid = threadIdx.x;
    const int lane = tid & 63, w = tid >> 6;     // 8 waves
    const int wm = w & 3, wn = w >> 2;           // 4M x 2N, wave tile 32x64
    const int hi = lane >> 4, llo = lane & 15;
    const int lrow = lane >> 3;
    const int lswz = ((lane & 7) ^ (lrow & 7)) * 8;
    const int fc0 = (hi ^ (llo & 7)) * 8;
    const int fc1 = ((hi + 4) ^ (llo & 7)) * 8;

    floatx4 acc[2][4];
    #pragma unroll
    for (int i = 0; i < 2; ++i)
        #pragma unroll
        for (int j = 0; j < 4; ++j)
            #pragma unroll
            for (int r = 0; r < 4; ++r) acc[i][j][r] = 0.0f;

    const size_t a_base = (size_t)(m0 + w * 16 + lrow) * C_DIM + lswz;
    const size_t b_base = (size_t)(n0 + w * 16 + lrow) * C_DIM + lswz;

    auto STAGE = [&](int bsel, int kt) {
        const int c0 = kt * 64;
        short* Ad = smem + bsel * 8192;
        short* Bd = smem + 16384 + bsel * 8192;
        #pragma unroll
        for (int p = 0; p < 2; ++p) {
            gld16(attb + a_base + (size_t)p * 8 * C_DIM + c0, &Ad[(w * 16 + p * 8) * 64]);
            gld16(wpt  + b_base + (size_t)p * 8 * C_DIM + c0, &Bd[(w * 16 + p * 8) * 64]);
        }
    };

    STAGE(0, 0);
    __syncthreads();

    for (int kt = 0; kt < 16; ++kt) {
        const int cur = kt & 1;
        if (kt < 15) STAGE(cur ^ 1, kt + 1);

        const short* As = smem + cur * 8192;
        const short* Bs = smem + 16384 + cur * 8192;

        short8 af[2][2];
        #pragma unroll
        for (int mi = 0; mi < 2; ++mi) {
            const int row = wm * 32 + mi * 16 + llo;
            af[mi][0] = *(const short8*)(&As[row * 64 + fc0]);
            af[mi][1] = *(const short8*)(&As[row * 64 + fc1]);
        }
        #pragma unroll
        for (int ni = 0; ni < 4; ++ni) {
            const int row = wn * 64 + ni * 16 + llo;
            short8 b0 = *(const short8*)(&Bs[row * 64 + fc0]);
            short8 b1 = *(const short8*)(&Bs[row * 64 + fc1]);
            #pragma unroll
            for (int mi = 0; mi < 2; ++mi) {
                acc[mi][ni] = __builtin_amdgcn_mfma_f32_16x16x32_bf16(af[mi][0], b0, acc[mi][ni], 0, 0, 0);
                acc[mi][ni] = __builtin_amdgcn_mfma_f32_16x16x32_bf16(af[mi][1], b1, acc[mi][ni], 0, 0, 0);
            }
        }
        __syncthreads();
    }

    #pragma unroll
    for (int ni = 0; ni < 4; ++ni) {
        const int n = n0 + wn * 64 + ni * 16 + llo;
        const float bias = bp[n];
        #pragma unroll
        for (int mi = 0; mi < 2; ++mi)
            #pragma unroll
            for (int r = 0; r < 4; ++r) {
                int m = m0 + wm * 32 + mi * 16 + hi * 4 + r;
                out[(size_t)m * C_DIM + n] = acc[mi][ni][r] + bias;
            }
    }
}

// ---------------------------------------------------------------------------
extern "C" void kernel_launch(void* const* d_in, const int* in_sizes, int n_in,
                              void* d_out, int out_size, void* d_ws, size_t ws_size,
                              hipStream_t stream) {
    const float* x  = (const float*)d_in[0];
    const float* Wq = (const float*)d_in[1];
    const float* Wk = (const float*)d_in[2];
    const float* Wv = (const float*)d_in[3];
    const float* Wp = (const float*)d_in[4];
    const float* bp = (const float*)d_in[5];
    float* out = (float*)d_out;

    short* xb   = (short*)d_ws;
    short* wt   = xb  + (size_t)M_TOT * C_DIM;
    short* wpt  = wt  + (size_t)3 * H_NUM * HD * C_DIM;
    short* qb   = wpt + (size_t)C_DIM * C_DIM;
    short* kb   = qb  + (size_t)M_TOT * C_DIM;
    short* vtb  = kb  + (size_t)M_TOT * C_DIM;
    short* attb = vtb + (size_t)M_TOT * C_DIM;

    static bool attr_done = false;
    if (!attr_done) {
        (void)hipFuncSetAttribute((const void*)qkv_k,
                                  hipFuncAttributeMaxDynamicSharedMemorySize,
                                  114688);
        attr_done = true;
    }

    prep_k<<<dim3(5120), 256, 0, stream>>>(x, Wq, Wk, Wv, Wp, xb, wt, wpt);
    qkv_k <<<dim3(256), 512, 114688, stream>>>(xb, wt, qb, kb, vtb);
    attn_k<<<dim3(BH_N, 16), 512, 0, stream>>>(qb, kb, vtb, attb);
    proj_k<<<dim3(M_TOT / 128, C_DIM / 128), 512, 0, stream>>>(attb, wpt, bp, out);
}